// Round 2
// baseline (15275.534 us; speedup 1.0000x reference)
//
#include <hip/hip_runtime.h>
#include <hip/hip_bf16.h>
#include <math.h>

#define NTOK   1024
#define CDIM   768
#define C3     2304
#define HEADS  12
#define DHEAD  64
#define NEXP   8
#define FDIM   3072
#define NLAYER 12
#define VOCAB  50257
#define TSEQ   128
#define EPSV   1e-5f
#define CAP    1024   // max tokens per expert
#define LDP    132    // padded LDS row (128 + 4), keeps 16B alignment (132*4=528)

// ---------------------------------------------------------------- reductions
__device__ __forceinline__ float block_sum256(float v, float* red) {
    #pragma unroll
    for (int o = 32; o; o >>= 1) v += __shfl_xor(v, o);
    int wid = threadIdx.x >> 6;
    if ((threadIdx.x & 63) == 0) red[wid] = v;
    __syncthreads();
    float r = red[0] + red[1] + red[2] + red[3];
    __syncthreads();
    return r;
}

// ---------------------------------------------------------------- embedding
__global__ __launch_bounds__(256) void k_embed(const int* __restrict__ idx,
        const float* __restrict__ tok, const float* __restrict__ pos,
        float* __restrict__ x) {
    int i = blockIdx.x * 256 + threadIdx.x;          // over NTOK*CDIM
    int n = i / CDIM, c = i - n * CDIM;
    int t = n & (TSEQ - 1);
    x[i] = tok[(size_t)idx[n] * CDIM + c] + pos[t * CDIM + c];
}

// ---------------------------------------------------------------- layernorm
__global__ __launch_bounds__(256) void k_ln(const float* __restrict__ x,
        const float* __restrict__ s, const float* __restrict__ b,
        float* __restrict__ y) {
    __shared__ float red[4];
    int n = blockIdx.x;
    const float* xr = x + (size_t)n * CDIM;
    int t = threadIdx.x;
    float v0 = xr[t], v1 = xr[t + 256], v2 = xr[t + 512];
    float mu = block_sum256(v0 + v1 + v2, red) * (1.f / CDIM);
    float d0 = v0 - mu, d1 = v1 - mu, d2 = v2 - mu;
    float var = block_sum256(d0 * d0 + d1 * d1 + d2 * d2, red) * (1.f / CDIM);
    float rs = rsqrtf(var + EPSV);
    float* yr = y + (size_t)n * CDIM;
    yr[t]       = d0 * rs * s[t]       + b[t];
    yr[t + 256] = d1 * rs * s[t + 256] + b[t + 256];
    yr[t + 512] = d2 * rs * s[t + 512] + b[t + 512];
}

// ---------------------------------------------------------------- attention
// One block per (batch, head). K,V staged in LDS (64 KiB). One thread per
// query row, online softmax, causal by loop bound. fp32 throughout.
__global__ __launch_bounds__(128) void k_attn(const float* __restrict__ qkv,
                                              float* __restrict__ out) {
    __shared__ float Ks[TSEQ][DHEAD];
    __shared__ float Vs[TSEQ][DHEAD];
    int b = blockIdx.x / HEADS, h = blockIdx.x % HEADS;
    const float* base = qkv + (size_t)b * TSEQ * C3 + h * DHEAD;
    for (int i = threadIdx.x; i < TSEQ * DHEAD; i += 128) {
        int j = i >> 6, d = i & 63;
        Ks[j][d] = base[j * C3 + CDIM + d];
        Vs[j][d] = base[j * C3 + 2 * CDIM + d];
    }
    __syncthreads();
    int r = threadIdx.x;
    const float* qrow = base + r * C3;
    float4 q[16];
    #pragma unroll
    for (int d4 = 0; d4 < 16; d4++) q[d4] = *(const float4*)(qrow + d4 * 4);
    float4 acc[16];
    #pragma unroll
    for (int i = 0; i < 16; i++) acc[i] = make_float4(0.f, 0.f, 0.f, 0.f);
    float m = -INFINITY, l = 0.f;
    for (int j = 0; j <= r; j++) {
        float s = 0.f;
        #pragma unroll
        for (int d4 = 0; d4 < 16; d4++) {
            float4 kv = *(const float4*)&Ks[j][d4 * 4];   // j uniform -> broadcast
            s += q[d4].x * kv.x + q[d4].y * kv.y + q[d4].z * kv.z + q[d4].w * kv.w;
        }
        s *= 0.125f;                                      // D^-0.5
        float mn = fmaxf(m, s);
        float corr = __expf(m - mn);                      // exp(-inf)=0 first iter
        float p = __expf(s - mn);
        l = l * corr + p;
        #pragma unroll
        for (int d4 = 0; d4 < 16; d4++) {
            float4 vv = *(const float4*)&Vs[j][d4 * 4];
            acc[d4].x = acc[d4].x * corr + p * vv.x;
            acc[d4].y = acc[d4].y * corr + p * vv.y;
            acc[d4].z = acc[d4].z * corr + p * vv.z;
            acc[d4].w = acc[d4].w * corr + p * vv.w;
        }
        m = mn;
    }
    float inv = 1.f / l;
    float* orow = out + ((size_t)b * TSEQ + r) * CDIM + h * DHEAD;   // [b,q,h,d]
    #pragma unroll
    for (int d4 = 0; d4 < 16; d4++) {
        orow[d4 * 4 + 0] = acc[d4].x * inv;
        orow[d4 * 4 + 1] = acc[d4].y * inv;
        orow[d4 * 4 + 2] = acc[d4].z * inv;
        orow[d4 * 4 + 3] = acc[d4].w * inv;
    }
}

// ---------------------------------------------------------------- tiled GEMM
// C[M,N] = A[M,K] @ B[N,K]^T  (row-major; B is a weight matrix)
// 128x128 tile, BK=16, 256 threads, 8x8 micro-tile (split fragments at +64).
// MODE 0: plain (qkv)            MODE 1: += residual aux (proj, out==x)
// MODE 2: N-bounds (lm head)     MODE 3: MoE w1, gathered rows, +bias, gelu
// MODE 4: MoE w2, entry rows, +bias
template<int MODE>
__global__ __launch_bounds__(256) void k_gemm(const float* __restrict__ A,
        const float* __restrict__ Bm, float* __restrict__ out,
        const float* __restrict__ aux, int Nn, int K,
        const int* __restrict__ token_list, const int* __restrict__ counts,
        const int* __restrict__ offsets) {
    __shared__ float As[16][LDP];    // [k][row], transposed store, padded
    __shared__ float Bs[16][LDP];    // [k][col]
    int e = 0, basei = 0, count = 0;
    int row0 = blockIdx.y * 128, col0 = blockIdx.x * 128;
    const float* Bptr = Bm;
    if constexpr (MODE == 3 || MODE == 4) {
        e = blockIdx.z;
        count = counts[e];
        if (row0 >= count) return;                     // uniform early-exit
        basei = offsets[e];
        Bptr = Bm + (size_t)e * (size_t)FDIM * CDIM;   // F*C == C*F elements
    }
    int tid = threadIdx.x;
    int lrow = tid >> 2;            // 0..63
    int lk4  = (tid & 3) * 4;       // 0,4,8,12

    // A source rows (lrow and lrow+64)
    int p0 = row0 + lrow, p1 = p0 + 64;
    bool av0 = true, av1 = true;
    int ar0, ar1;
    if constexpr (MODE == 3) {
        av0 = p0 < count; av1 = p1 < count;
        ar0 = av0 ? token_list[e * CAP + p0] : 0;
        ar1 = av1 ? token_list[e * CAP + p1] : 0;
    } else if constexpr (MODE == 4) {
        av0 = p0 < count; av1 = p1 < count;
        ar0 = basei + (av0 ? p0 : 0);
        ar1 = basei + (av1 ? p1 : 0);
    } else { ar0 = p0; ar1 = p1; }
    // B source rows (weight rows = output cols)
    int bc0 = col0 + lrow, bc1 = bc0 + 64;
    bool bv0 = (MODE == 2) ? (bc0 < Nn) : true;
    bool bv1 = (MODE == 2) ? (bc1 < Nn) : true;
    const float* arp0 = A + (size_t)ar0 * K + lk4;
    const float* arp1 = A + (size_t)ar1 * K + lk4;
    const float* brp0 = Bptr + (size_t)(bv0 ? bc0 : 0) * K + lk4;
    const float* brp1 = Bptr + (size_t)(bv1 ? bc1 : 0) * K + lk4;

    int tx = tid & 15, ty = tid >> 4;     // 16x16 compute grid
    float acc[8][8] = {};
    const float4 f40 = make_float4(0.f, 0.f, 0.f, 0.f);

    for (int k0 = 0; k0 < K; k0 += 16) {
        float4 a0 = av0 ? *(const float4*)(arp0 + k0) : f40;
        float4 a1 = av1 ? *(const float4*)(arp1 + k0) : f40;
        float4 b0 = bv0 ? *(const float4*)(brp0 + k0) : f40;
        float4 b1 = bv1 ? *(const float4*)(brp1 + k0) : f40;
        __syncthreads();                       // prev iter done reading LDS
        float a0v[4], a1v[4], b0v[4], b1v[4];
        *(float4*)a0v = a0; *(float4*)a1v = a1;
        *(float4*)b0v = b0; *(float4*)b1v = b1;
        #pragma unroll
        for (int j = 0; j < 4; j++) {
            As[lk4 + j][lrow]      = a0v[j];
            As[lk4 + j][lrow + 64] = a1v[j];
            Bs[lk4 + j][lrow]      = b0v[j];
            Bs[lk4 + j][lrow + 64] = b1v[j];
        }
        __syncthreads();
        #pragma unroll
        for (int kk = 0; kk < 16; kk++) {
            float4 aA = *(const float4*)&As[kk][ty * 4];        // broadcast x16
            float4 aB = *(const float4*)&As[kk][64 + ty * 4];
            float4 bA = *(const float4*)&Bs[kk][tx * 4];        // 2-way, free
            float4 bB = *(const float4*)&Bs[kk][64 + tx * 4];
            float ar[8] = {aA.x, aA.y, aA.z, aA.w, aB.x, aB.y, aB.z, aB.w};
            float br[8] = {bA.x, bA.y, bA.z, bA.w, bB.x, bB.y, bB.z, bB.w};
            #pragma unroll
            for (int i = 0; i < 8; i++)
                #pragma unroll
                for (int j = 0; j < 8; j++)
                    acc[i][j] += ar[i] * br[j];
        }
    }

    // ---- epilogue: rows {row0 + ih*64 + ty*4 + i}, cols {col0 + jh*64 + tx*4 + j}
    #pragma unroll
    for (int ih = 0; ih < 2; ih++) {
        #pragma unroll
        for (int i = 0; i < 4; i++) {
            int pr = row0 + ih * 64 + ty * 4 + i;   // row (or pos-in-expert)
            if constexpr (MODE == 3 || MODE == 4) { if (pr >= count) continue; }
            size_t orow;
            if constexpr (MODE == 3)      orow = (size_t)(basei + pr) * FDIM;
            else if constexpr (MODE == 4) orow = (size_t)(basei + pr) * CDIM;
            else                          orow = (size_t)pr * Nn;
            #pragma unroll
            for (int jh = 0; jh < 2; jh++) {
                int cc = col0 + jh * 64 + tx * 4;
                if constexpr (MODE == 2) {
                    #pragma unroll
                    for (int j = 0; j < 4; j++)
                        if (cc + j < Nn) out[orow + cc + j] = acc[ih * 4 + i][jh * 4 + j];
                } else {
                    float4 v = make_float4(acc[ih * 4 + i][jh * 4 + 0],
                                           acc[ih * 4 + i][jh * 4 + 1],
                                           acc[ih * 4 + i][jh * 4 + 2],
                                           acc[ih * 4 + i][jh * 4 + 3]);
                    if constexpr (MODE == 1) {
                        float4 r = *(const float4*)&aux[orow + cc];
                        v.x += r.x; v.y += r.y; v.z += r.z; v.w += r.w;
                    }
                    if constexpr (MODE == 3) {
                        float4 bb = *(const float4*)&aux[e * FDIM + cc];
                        v.x += bb.x; v.y += bb.y; v.z += bb.z; v.w += bb.w;
                        v.x = 0.5f * v.x * (1.f + erff(v.x * 0.70710678118654752f));
                        v.y = 0.5f * v.y * (1.f + erff(v.y * 0.70710678118654752f));
                        v.z = 0.5f * v.z * (1.f + erff(v.z * 0.70710678118654752f));
                        v.w = 0.5f * v.w * (1.f + erff(v.w * 0.70710678118654752f));
                    }
                    if constexpr (MODE == 4) {
                        float4 bb = *(const float4*)&aux[e * CDIM + cc];
                        v.x += bb.x; v.y += bb.y; v.z += bb.z; v.w += bb.w;
                    }
                    *(float4*)&out[orow + cc] = v;
                }
            }
        }
    }
}

// ---------------------------------------------------------------- router
__global__ __launch_bounds__(64) void k_router(const float* __restrict__ y,
        const float* __restrict__ rw, int* __restrict__ cnts,
        int* __restrict__ r_e, int* __restrict__ r_p, float* __restrict__ r_wt,
        int* __restrict__ tlist) {
    int n = blockIdx.x, lane = threadIdx.x;
    const float* yr = y + (size_t)n * CDIM;
    float logit[NEXP];
    #pragma unroll
    for (int e = 0; e < NEXP; e++) {
        const float* w = rw + e * CDIM;
        float s = 0.f;
        for (int c = lane; c < CDIM; c += 64) s += yr[c] * w[c];
        #pragma unroll
        for (int o = 32; o; o >>= 1) s += __shfl_xor(s, o);
        logit[e] = s;
    }
    if (lane == 0) {
        float mx = logit[0];
        #pragma unroll
        for (int e = 1; e < NEXP; e++) mx = fmaxf(mx, logit[e]);
        float pe[NEXP];
        #pragma unroll
        for (int e = 0; e < NEXP; e++) pe[e] = __expf(logit[e] - mx);
        // top-2 (first-index tie-break like lax.top_k); softmax denom cancels
        int i0 = 0;
        #pragma unroll
        for (int e = 1; e < NEXP; e++) if (pe[e] > pe[i0]) i0 = e;
        int i1 = (i0 == 0) ? 1 : 0;
        #pragma unroll
        for (int e = 0; e < NEXP; e++) if (e != i0 && pe[e] > pe[i1]) i1 = e;
        float w0 = pe[i0], w1 = pe[i1];
        float inv = 1.f / (w0 + w1);
        w0 *= inv; w1 *= inv;
        int p0 = atomicAdd(&cnts[i0], 1);
        int p1 = atomicAdd(&cnts[i1], 1);
        tlist[i0 * CAP + p0] = n;
        tlist[i1 * CAP + p1] = n;
        r_e[2 * n] = i0; r_e[2 * n + 1] = i1;
        r_p[2 * n] = p0; r_p[2 * n + 1] = p1;
        r_wt[2 * n] = w0; r_wt[2 * n + 1] = w1;
    }
}

__global__ void k_zero8(int* c) { if (threadIdx.x < NEXP) c[threadIdx.x] = 0; }

__global__ void k_scan(const int* __restrict__ c, int* __restrict__ o) {
    if (threadIdx.x == 0) {
        int s = 0;
        for (int e = 0; e < NEXP; e++) { o[e] = s; s += c[e]; }
    }
}

// ---------------------------------------------------------------- combine
__global__ __launch_bounds__(256) void k_combine(float* __restrict__ x,
        const float* __restrict__ yslot, const int* __restrict__ r_e,
        const int* __restrict__ r_p, const float* __restrict__ r_wt,
        const int* __restrict__ offs) {
    int i = blockIdx.x * 256 + threadIdx.x;            // over NTOK*CDIM
    int n = i / CDIM, c = i - n * CDIM;
    int g0 = offs[r_e[2 * n]]     + r_p[2 * n];
    int g1 = offs[r_e[2 * n + 1]] + r_p[2 * n + 1];
    x[i] += r_wt[2 * n]     * yslot[(size_t)g0 * CDIM + c]
          + r_wt[2 * n + 1] * yslot[(size_t)g1 * CDIM + c];
}

// ---------------------------------------------------------------- launch
extern "C" void kernel_launch(void* const* d_in, const int* in_sizes, int n_in,
                              void* d_out, int out_size, void* d_ws, size_t ws_size,
                              hipStream_t stream) {
    const int*   idx   = (const int*)d_in[0];
    const float* tokw  = (const float*)d_in[1];
    const float* posw  = (const float*)d_in[2];
    const float* ln1s  = (const float*)d_in[3];
    const float* ln1b  = (const float*)d_in[4];
    const float* qkvw  = (const float*)d_in[5];
    const float* projw = (const float*)d_in[6];
    const float* ln2s  = (const float*)d_in[7];
    const float* ln2b  = (const float*)d_in[8];
    const float* routw = (const float*)d_in[9];
    const float* w1    = (const float*)d_in[10];
    const float* b1    = (const float*)d_in[11];
    const float* w2    = (const float*)d_in[12];
    const float* b2    = (const float*)d_in[13];
    const float* lnfs  = (const float*)d_in[14];
    const float* lnfb  = (const float*)d_in[15];
    float* out = (float*)d_out;

    // workspace carve (floats, all 16B-aligned; ~50.4 MB total)
    float* x     = (float*)d_ws;
    float* ybuf  = x     + (size_t)NTOK * CDIM;
    float* qkvb  = ybuf  + (size_t)NTOK * CDIM;
    float* attb  = qkvb  + (size_t)NTOK * C3;
    float* hbuf  = attb  + (size_t)NTOK * CDIM;        // 2048 x FDIM
    float* yslot = hbuf  + (size_t)2 * NTOK * FDIM;    // 2048 x CDIM
    float* r_wt  = yslot + (size_t)2 * NTOK * CDIM;
    int*   r_e   = (int*)(r_wt + 2 * NTOK);
    int*   r_p   = r_e + 2 * NTOK;
    int*   cnts  = r_p + 2 * NTOK;
    int*   offs  = cnts + NEXP;
    int*   tlist = offs + NEXP;                        // NEXP x CAP

    k_embed<<<dim3(NTOK * CDIM / 256), dim3(256), 0, stream>>>(idx, tokw, posw, x);

    for (int l = 0; l < NLAYER; l++) {
        k_ln<<<dim3(NTOK), dim3(256), 0, stream>>>(x, ln1s + l * CDIM, ln1b + l * CDIM, ybuf);
        k_gemm<0><<<dim3(C3 / 128, NTOK / 128), dim3(256), 0, stream>>>(
            ybuf, qkvw + (size_t)l * C3 * CDIM, qkvb, nullptr, C3, CDIM,
            nullptr, nullptr, nullptr);
        k_attn<<<dim3((NTOK / TSEQ) * HEADS), dim3(128), 0, stream>>>(qkvb, attb);
        k_gemm<1><<<dim3(CDIM / 128, NTOK / 128), dim3(256), 0, stream>>>(
            attb, projw + (size_t)l * CDIM * CDIM, x, x, CDIM, CDIM,
            nullptr, nullptr, nullptr);
        k_ln<<<dim3(NTOK), dim3(256), 0, stream>>>(x, ln2s + l * CDIM, ln2b + l * CDIM, ybuf);
        k_zero8<<<dim3(1), dim3(64), 0, stream>>>(cnts);
        k_router<<<dim3(NTOK), dim3(64), 0, stream>>>(
            ybuf, routw + (size_t)l * NEXP * CDIM, cnts, r_e, r_p, r_wt, tlist);
        k_scan<<<dim3(1), dim3(1), 0, stream>>>(cnts, offs);
        k_gemm<3><<<dim3(FDIM / 128, CAP / 128, NEXP), dim3(256), 0, stream>>>(
            ybuf, w1 + (size_t)l * NEXP * FDIM * CDIM, hbuf,
            b1 + (size_t)l * NEXP * FDIM, FDIM, CDIM, tlist, cnts, offs);
        k_gemm<4><<<dim3(CDIM / 128, CAP / 128, NEXP), dim3(256), 0, stream>>>(
            hbuf, w2 + (size_t)l * NEXP * CDIM * FDIM, yslot,
            b2 + (size_t)l * NEXP * CDIM, CDIM, FDIM, nullptr, cnts, offs);
        k_combine<<<dim3(NTOK * CDIM / 256), dim3(256), 0, stream>>>(
            x, yslot, r_e, r_p, r_wt, offs);
    }

    k_ln<<<dim3(NTOK), dim3(256), 0, stream>>>(x, lnfs, lnfb, ybuf);
    k_gemm<2><<<dim3((VOCAB + 127) / 128, NTOK / 128), dim3(256), 0, stream>>>(
        ybuf, tokw, out, nullptr, VOCAB, CDIM, nullptr, nullptr, nullptr);
}